// Round 2
// baseline (2511.484 us; speedup 1.0000x reference)
//
#include <hip/hip_runtime.h>
#include <math.h>

#define BATCH 32
#define NA 100000
#define NC 81
#define NBUCK 32768
#define NEG_RATIO 3

#define UNROLL 4
#define ITERS 8                       // anchors per wave = UNROLL*ITERS = 32
#define WAVES_PER_BLOCK 4
#define ANCH_PER_WAVE (UNROLL * ITERS)                    // 32
#define ANCH_PER_BLOCK (WAVES_PER_BLOCK * ANCH_PER_WAVE)  // 128

// ---------------------------------------------------------------------------
// k1: wave-per-anchor. Lane l covers class l (l<64) and class 64+l (l<17).
// lse = log(sum exp(x)) -- inputs are N(0,1), no max-shift needed (|x|<~6).
// Positives: CE + smooth-L1 accumulated (wave-uniform). Negatives: value ->
// neg_vals + 32768-bucket histogram (float bits monotone for v>=0).
// ---------------------------------------------------------------------------
__global__ __launch_bounds__(256) void k1_main(
    const float* __restrict__ loc_p, const float* __restrict__ cls_p,
    const float* __restrict__ loc_t, const int* __restrict__ cls_t,
    float* __restrict__ neg_vals, int* __restrict__ hist,
    int* __restrict__ pos_count, float* __restrict__ sl1_sum,
    float* __restrict__ ce_sum)
{
    const int b = blockIdx.y;
    const int wave = threadIdx.x >> 6;
    const int l = threadIdx.x & 63;
    const int wave_a0 = blockIdx.x * ANCH_PER_BLOCK + wave * ANCH_PER_WAVE;

    float sl1_acc = 0.0f, ce_acc = 0.0f;
    int pos_cnt = 0;

    for (int it = 0; it < ITERS; ++it) {
        const int a0 = wave_a0 + it * UNROLL;
        if (a0 >= NA) break;
        const size_t idx0 = (size_t)b * NA + a0;
        const float* __restrict__ xp = cls_p + idx0 * NC;

        // coalesced loads: 2 per anchor (256B + 68B contiguous)
        float v0[UNROLL], v1[UNROLL], e[UNROLL];
        #pragma unroll
        for (int j = 0; j < UNROLL; ++j) {
            const bool va = (a0 + j) < NA;
            v0[j] = va ? xp[j * NC + l] : 0.0f;
            v1[j] = (va && l < 17) ? xp[j * NC + 64 + l] : 0.0f;
        }
        // target ids: lanes 0..3 load, broadcast by shuffle
        int tl = (l < UNROLL && (a0 + l) < NA) ? cls_t[idx0 + l] : 0;

        #pragma unroll
        for (int j = 0; j < UNROLL; ++j)
            e[j] = __expf(v0[j]) + ((l < 17) ? __expf(v1[j]) : 0.0f);

        // wave sum-reduce (all lanes end with the total)
        #pragma unroll
        for (int off = 1; off < 64; off <<= 1) {
            #pragma unroll
            for (int j = 0; j < UNROLL; ++j)
                e[j] += __shfl_xor(e[j], off, 64);
        }

        float w = -1.0f;  // per-lane batched neg_vals value (lanes 0..3)
        #pragma unroll
        for (int j = 0; j < UNROLL; ++j) {
            if ((a0 + j) >= NA) continue;
            const float lse = __logf(e[j]);
            const int t = __shfl(tl, j, 64);    // wave-uniform
            if (t != 0) {
                pos_cnt += 1;
                const float xt = (t < 64) ? __shfl(v0[j], t, 64)
                                          : __shfl(v1[j], t - 64, 64);
                ce_acc += lse - xt;
                const float4 lp = *(const float4*)(loc_p + (idx0 + j) * 4);
                const float4 lt = *(const float4*)(loc_t + (idx0 + j) * 4);
                float d, ad;
                d = lp.x - lt.x; ad = fabsf(d);
                sl1_acc += (ad < 1.0f) ? 0.5f * d * d : ad - 0.5f;
                d = lp.y - lt.y; ad = fabsf(d);
                sl1_acc += (ad < 1.0f) ? 0.5f * d * d : ad - 0.5f;
                d = lp.z - lt.z; ad = fabsf(d);
                sl1_acc += (ad < 1.0f) ? 0.5f * d * d : ad - 0.5f;
                d = lp.w - lt.w; ad = fabsf(d);
                sl1_acc += (ad < 1.0f) ? 0.5f * d * d : ad - 0.5f;
                // w stays -1 on lane j (positive sentinel)
            } else {
                const float x0 = __shfl(v0[j], 0, 64);
                const float nv = fmaxf(lse - x0, 0.0f);
                if (l == j) w = nv;
            }
        }

        // batched: one store inst + one atomic inst for the 4 anchors
        if (l < UNROLL && (a0 + l) < NA) {
            neg_vals[idx0 + l] = w;
            if (w >= 0.0f)
                atomicAdd(&hist[b * NBUCK + (int)(__float_as_uint(w) >> 17)], 1);
        }
    }

    // per-wave lane 0 holds the accumulators (values are wave-uniform)
    __shared__ float rs[WAVES_PER_BLOCK], rc[WAVES_PER_BLOCK];
    __shared__ int rp[WAVES_PER_BLOCK];
    if (l == 0) { rs[wave] = sl1_acc; rc[wave] = ce_acc; rp[wave] = pos_cnt; }
    __syncthreads();
    if (threadIdx.x == 0) {
        float a0s = 0.0f, a1s = 0.0f; int p = 0;
        #pragma unroll
        for (int wv = 0; wv < WAVES_PER_BLOCK; ++wv) {
            a0s += rs[wv]; a1s += rc[wv]; p += rp[wv];
        }
        if (p) atomicAdd(&pos_count[b], p);
        if (a0s != 0.0f) atomicAdd(&sl1_sum[b], a0s);
        if (a1s != 0.0f) atomicAdd(&ce_sum[b], a1s);
    }
}

// ---------------------------------------------------------------------------
// k2: per sample -- find threshold bucket T such that
// count(buckets > T) < k <= count(buckets >= T); store T and k_rem.
// ---------------------------------------------------------------------------
__global__ __launch_bounds__(256) void k2_select(
    const int* __restrict__ hist, const int* __restrict__ pos_count,
    int* __restrict__ Tbuck, int* __restrict__ krem)
{
    const int b = blockIdx.x;
    const int* __restrict__ h = hist + (size_t)b * NBUCK;
    __shared__ int chunk_sum[256];
    const int t = threadIdx.x;
    const int CH = NBUCK / 256;  // 128 buckets per thread
    int cs = 0;
    for (int j = 0; j < CH; ++j) cs += h[t * CH + j];
    chunk_sum[t] = cs;
    __syncthreads();

    if (t == 0) {
        const int np = pos_count[b];
        const int k = (np > 0) ? min(NEG_RATIO * np, NA - np) : 0;
        if (k <= 0) {
            Tbuck[b] = 0x7fffffff;
            krem[b] = 0;
        } else {
            int cum = 0;
            int c = 255;
            for (; c >= 0; --c) {
                if (cum + chunk_sum[c] >= k) break;
                cum += chunk_sum[c];
            }
            if (c < 0) {
                Tbuck[b] = 0;
                krem[b] = 0x7fffffff;
            } else {
                int T = 0;
                for (int j = CH - 1; j >= 0; --j) {
                    const int bi = c * CH + j;
                    if (cum + h[bi] >= k) { T = bi; break; }
                    cum += h[bi];
                }
                Tbuck[b] = T;
                krem[b] = k - cum;
            }
        }
    }
}

// ---------------------------------------------------------------------------
// k3: sum negatives with bucket > T; take exactly k_rem from bucket == T via
// atomic ticket counter (ties within one bucket differ by < bucket width).
// ---------------------------------------------------------------------------
__global__ __launch_bounds__(256) void k3_negsum(
    const float* __restrict__ neg_vals, const int* __restrict__ Tbuck,
    const int* __restrict__ krem, int* __restrict__ tie_cnt,
    float* __restrict__ neg_sum)
{
    const int b = blockIdx.y;
    const int a = blockIdx.x * blockDim.x + threadIdx.x;
    float add = 0.0f;
    if (a < NA) {
        const float v = neg_vals[(size_t)b * NA + a];
        if (v >= 0.0f) {
            const int buck = (int)(__float_as_uint(v) >> 17);
            const int T = Tbuck[b];
            if (buck > T) {
                add = v;
            } else if (buck == T) {
                const int old = atomicAdd(&tie_cnt[b], 1);
                if (old < krem[b]) add = v;
            }
        }
    }
    for (int off = 32; off > 0; off >>= 1) add += __shfl_down(add, off);
    if ((threadIdx.x & 63) == 0 && add != 0.0f) atomicAdd(&neg_sum[b], add);
}

// ---------------------------------------------------------------------------
// k4: combine per-sample pieces -> scalar output.
// ---------------------------------------------------------------------------
__global__ void k4_final(
    const int* __restrict__ pos_count, const float* __restrict__ sl1_sum,
    const float* __restrict__ ce_sum, const float* __restrict__ neg_sum,
    float* __restrict__ out)
{
    const int b = threadIdx.x;
    float v = 0.0f;
    if (b < BATCH) {
        const int np = pos_count[b];
        if (np > 0) {
            v = (sl1_sum[b] + ce_sum[b] + neg_sum[b]) / (float)np;
        }
    }
    for (int off = 32; off > 0; off >>= 1) v += __shfl_down(v, off);
    if (threadIdx.x == 0) out[0] = v;
}

extern "C" void kernel_launch(void* const* d_in, const int* in_sizes, int n_in,
                              void* d_out, int out_size, void* d_ws, size_t ws_size,
                              hipStream_t stream)
{
    const float* loc_p = (const float*)d_in[0];
    const float* cls_p = (const float*)d_in[1];
    const float* loc_t = (const float*)d_in[2];
    const int*   cls_t = (const int*)d_in[3];
    float* out = (float*)d_out;

    // workspace layout
    char* base = (char*)d_ws;
    float* neg_vals = (float*)base;
    size_t off = (size_t)BATCH * NA * sizeof(float);              // 12.8 MB
    int* hist = (int*)(base + off);
    off += (size_t)BATCH * NBUCK * sizeof(int);                   // 4 MB
    int*   pos_count = (int*)(base + off);   off += BATCH * sizeof(int);
    float* sl1_sum   = (float*)(base + off); off += BATCH * sizeof(float);
    float* ce_sum    = (float*)(base + off); off += BATCH * sizeof(float);
    float* neg_sum   = (float*)(base + off); off += BATCH * sizeof(float);
    int*   tie_cnt   = (int*)(base + off);   off += BATCH * sizeof(int);
    int*   Tbuck     = (int*)(base + off);   off += BATCH * sizeof(int);
    int*   krem      = (int*)(base + off);   off += BATCH * sizeof(int);

    // zero histogram + accumulators (contiguous region: hist..tie_cnt)
    const size_t zero_bytes =
        (size_t)BATCH * NBUCK * sizeof(int) + (size_t)5 * BATCH * sizeof(int);
    hipMemsetAsync(hist, 0, zero_bytes, stream);

    dim3 grid1((NA + ANCH_PER_BLOCK - 1) / ANCH_PER_BLOCK, BATCH);
    k1_main<<<grid1, 256, 0, stream>>>(loc_p, cls_p, loc_t, cls_t,
                                       neg_vals, hist, pos_count, sl1_sum, ce_sum);
    k2_select<<<BATCH, 256, 0, stream>>>(hist, pos_count, Tbuck, krem);
    dim3 grid3((NA + 255) / 256, BATCH);
    k3_negsum<<<grid3, 256, 0, stream>>>(neg_vals, Tbuck, krem, tie_cnt, neg_sum);
    k4_final<<<1, 64, 0, stream>>>(pos_count, sl1_sum, ce_sum, neg_sum, out);
}